// Round 5
// baseline (2319.838 us; speedup 1.0000x reference)
//
#include <hip/hip_runtime.h>

#define TPB 256
#define TC  128          // h3 output positions per chunk
#define NCH 8            // ceil(988 / TC)

// odd LDS strides: row starts spread across banks
#define SX 141           // x chunk length  (>= tc+12)
#define S1 137           // h1 length       (>= tc+8)
#define S2 133           // h2 length       (>= tc+4)
#define S3 129           // h3 length       (>= tc)
#define SM 141           // m buffer length (>= Lo+4, max tc+12)

// wbuf layout: [0..500) conv k | [500..510) conv b | [510..520) bn scale |
// [520..530) bn shift | [530..930) attn K | [930..950) attn b |
// [950..1000) attn dw | [1000..1010) attn db
__device__ __forceinline__ void load_stage_w(
    float* w, const float* ck, int ckn, const float* cb,
    const float* g, const float* be, const float* m, const float* v,
    const float* aK, int aKn, const float* ab,
    const float* adw, const float* adb)
{
  const int tid = threadIdx.x;
  for (int i = tid; i < ckn; i += TPB) w[i] = ck[i];
  if (tid < 10) {
    w[500 + tid] = cb[tid];
    float sc = g[tid] * rsqrtf(v[tid] + 1e-3f);
    w[510 + tid] = sc;
    w[520 + tid] = be[tid] - m[tid] * sc;
    w[1000 + tid] = adb[tid];
  }
  for (int i = tid; i < aKn; i += TPB) w[530 + i] = aK[i];
  if (tid < 20) w[930 + tid] = ab[tid];
  if (tid < 50) w[950 + tid] = adw[tid];
}

// One fused stage. ZERO per-thread arrays: rounds 1-4 all kept small
// per-thread aggregates and the compiler parked them in scratch
// (VGPR=84 << cap while GBs of HBM traffic flowed) -> fully scalarized.
// in : [(cin*2+h)*SIN + t]; out : [(c*2+o)*SOUT + t]
template <int CIN, int SIN, int SOUT>
__device__ __forceinline__ void run_stage(
    const float* __restrict__ in, float* __restrict__ out,
    float* __restrict__ mbuf, int Lo, const float* __restrict__ w)
{
  const float* ck    = w;
  const float* cb    = w + 500;
  const float* scale = w + 510;
  const float* shift = w + 520;
  const float* aK    = w + 530;
  const float* ab    = w + 930;
  const float* adw   = w + 950;
  const float* adb   = w + 1000;
  const int Li = Lo + 4;

  // ---- Phase A: m[i][o][t] -> mbuf. thread = (head-half, o, t).
#pragma unroll 1
  for (int idx = threadIdx.x; idx < 4 * Li; idx += TPB) {
    const int ih = idx & 1;
    const int o  = (idx >> 1) & 1;
    const int t  = idx >> 2;
    const int i0 = ih * 5;
    const float* inb = in + t;
#pragma unroll
    for (int j = 0; j < 5; ++j) {
      const int i = i0 + j;
      float acc = ab[i * 2 + o];
#pragma unroll
      for (int h = 0; h < 2; ++h)
#pragma unroll
        for (int ci = 0; ci < CIN; ++ci)
          acc += inb[(ci * 2 + h) * SIN] * aK[((i * 2 + h) * CIN + ci) * 2 + o];
      mbuf[(i * 2 + o) * SM + t] = acc;
    }
  }
  __syncthreads();

  // ---- Phase B: thread = (channel-half, o, t); 5 named scalar channels,
  // softmax joined across the adjacent-lane pair via shfl_xor(1).
#pragma unroll 1
  for (int idx = threadIdx.x; idx < 4 * Lo; idx += TPB) {
    const int half = idx & 1;
    const int o    = (idx >> 1) & 1;
    const int t    = idx >> 2;
    const int c0   = half * 5;

    // depthwise attention logits
    float y0 = adb[c0 + 0], y1 = adb[c0 + 1], y2 = adb[c0 + 2],
          y3 = adb[c0 + 3], y4 = adb[c0 + 4];
    const float* mb = mbuf + (c0 * 2 + o) * SM + t;
#pragma unroll
    for (int wk = 0; wk < 5; ++wk) {
      const float* aw = adw + wk * 10 + c0;
      y0 += mb[0 * 2 * SM + wk] * aw[0];
      y1 += mb[1 * 2 * SM + wk] * aw[1];
      y2 += mb[2 * 2 * SM + wk] * aw[2];
      y3 += mb[3 * 2 * SM + wk] * aw[3];
      y4 += mb[4 * 2 * SM + wk] * aw[4];
    }

    // conv (1,5) valid, CIN -> 5 channels
    float cv0 = cb[c0 + 0], cv1 = cb[c0 + 1], cv2 = cb[c0 + 2],
          cv3 = cb[c0 + 3], cv4 = cb[c0 + 4];
    const float* inb = in + o * SIN + t;
#pragma unroll
    for (int wk = 0; wk < 5; ++wk)
#pragma unroll
      for (int ci = 0; ci < CIN; ++ci) {
        const float xin = inb[ci * 2 * SIN + wk];
        const float* kk = ck + (wk * CIN + ci) * 10 + c0;
        cv0 += xin * kk[0];
        cv1 += xin * kk[1];
        cv2 += xin * kk[2];
        cv3 += xin * kk[3];
        cv4 += xin * kk[4];
      }

    // softmax over 10 heads: pairwise exchange of max and sum
    float mx = fmaxf(fmaxf(fmaxf(y0, y1), fmaxf(y2, y3)), y4);
    mx = fmaxf(mx, __shfl_xor(mx, 1, 64));
    const float e0 = __expf(y0 - mx), e1 = __expf(y1 - mx),
                e2 = __expf(y2 - mx), e3 = __expf(y3 - mx),
                e4 = __expf(y4 - mx);
    float sm = e0 + e1 + e2 + e3 + e4;
    sm += __shfl_xor(sm, 1, 64);
    const float inv = 1.0f / sm;

    float* ob = out + (c0 * 2 + o) * SOUT + t;
    float b0;
    b0 = cv0 * scale[c0 + 0] + shift[c0 + 0]; b0 = (b0 >= 0.f) ? b0 : 0.2f * b0; ob[0 * 2 * SOUT] = b0 * e0 * inv;
    b0 = cv1 * scale[c0 + 1] + shift[c0 + 1]; b0 = (b0 >= 0.f) ? b0 : 0.2f * b0; ob[1 * 2 * SOUT] = b0 * e1 * inv;
    b0 = cv2 * scale[c0 + 2] + shift[c0 + 2]; b0 = (b0 >= 0.f) ? b0 : 0.2f * b0; ob[2 * 2 * SOUT] = b0 * e2 * inv;
    b0 = cv3 * scale[c0 + 3] + shift[c0 + 3]; b0 = (b0 >= 0.f) ? b0 : 0.2f * b0; ob[3 * 2 * SOUT] = b0 * e3 * inv;
    b0 = cv4 * scale[c0 + 4] + shift[c0 + 4]; b0 = (b0 >= 0.f) ? b0 : 0.2f * b0; ob[4 * 2 * SOUT] = b0 * e4 * inv;
  }
  __syncthreads();
}

__global__ __launch_bounds__(TPB, 3) void vignet_kernel(
    const float* __restrict__ x,
    const float* __restrict__ c1k, const float* __restrict__ c1b,
    const float* __restrict__ c2k, const float* __restrict__ c2b,
    const float* __restrict__ c3k, const float* __restrict__ c3b,
    const float* __restrict__ c4k, const float* __restrict__ c4b,
    const float* __restrict__ g1, const float* __restrict__ be1,
    const float* __restrict__ m1, const float* __restrict__ v1,
    const float* __restrict__ g2, const float* __restrict__ be2,
    const float* __restrict__ m2, const float* __restrict__ v2,
    const float* __restrict__ g3, const float* __restrict__ be3,
    const float* __restrict__ m3, const float* __restrict__ v3,
    const float* __restrict__ dnsw,
    const float* __restrict__ a1K, const float* __restrict__ a1b,
    const float* __restrict__ a1dw, const float* __restrict__ a1db,
    const float* __restrict__ a2K, const float* __restrict__ a2b,
    const float* __restrict__ a2dw, const float* __restrict__ a2db,
    const float* __restrict__ a3K, const float* __restrict__ a3b,
    const float* __restrict__ a3dw, const float* __restrict__ a3db,
    float* __restrict__ ws)
{
  __shared__ float xbuf[2 * SX];
  __shared__ float bufA[20 * S1];   // h1, then h3
  __shared__ float bufB[20 * S2];   // h2
  __shared__ float mbuf[20 * SM];
  __shared__ float wbuf[1024];
  __shared__ float red[4];

  const int b     = blockIdx.x / NCH;
  const int chunk = blockIdx.x - b * NCH;
  const int base  = chunk * TC;
  const int tc    = min(TC, 988 - base);
  const int tid   = threadIdx.x;

  // x chunk -> xbuf[h*SX + t], t in [0, tc+12)
  const int Lx = tc + 12;
  for (int idx = tid; idx < 2 * Lx; idx += TPB) {
    const int h = (idx >= Lx) ? 1 : 0;
    const int t = idx - h * Lx;
    xbuf[h * SX + t] = x[b * 2000 + h * 1000 + base + t];
  }
  load_stage_w(wbuf, c1k, 50, c1b, g1, be1, m1, v1, a1K, 40, a1b, a1dw, a1db);
  __syncthreads();

  run_stage<1, SX, S1>(xbuf, bufA, mbuf, tc + 8, wbuf);   // h1 -> bufA
  load_stage_w(wbuf, c2k, 500, c2b, g2, be2, m2, v2, a2K, 400, a2b, a2dw, a2db);
  __syncthreads();

  run_stage<10, S1, S2>(bufA, bufB, mbuf, tc + 4, wbuf);  // h2 -> bufB
  load_stage_w(wbuf, c3k, 500, c3b, g3, be3, m3, v3, a3K, 400, a3b, a3dw, a3db);
  __syncthreads();

  run_stage<10, S2, S3>(bufB, bufA, mbuf, tc, wbuf);      // h3 -> bufA

  // stage4 weights: c4k -> [0..400), c4b -> [400..420)
  for (int i = tid; i < 400; i += TPB) wbuf[i] = c4k[i];
  if (tid < 20) wbuf[400 + tid] = c4b[tid];
  __syncthreads();

  // conv4 (2,1) -> lrelu -> dot with dns_w slice; scalar accumulators only.
  float partial = 0.f;
#pragma unroll 1
  for (int idx = tid; idx < 2 * tc; idx += TPB) {
    const int half = (idx >= tc) ? 1 : 0;
    const int t    = idx - half * tc;
    const float* dwp = dnsw + (base + t) * 20 + half * 10;
    float dot = 0.f;
#pragma unroll
    for (int cc = 0; cc < 10; ++cc) {
      const int ccg = half * 10 + cc;
      float acc = wbuf[400 + ccg];
#pragma unroll
      for (int h = 0; h < 2; ++h)
#pragma unroll
        for (int ci = 0; ci < 10; ++ci)
          acc += bufA[(ci * 2 + h) * S3 + t] * wbuf[(h * 10 + ci) * 20 + ccg];
      acc = (acc >= 0.f) ? acc : 0.2f * acc;
      dot += acc * dwp[cc];
    }
    partial += dot;
  }

#pragma unroll
  for (int off = 32; off > 0; off >>= 1)
    partial += __shfl_down(partial, off, 64);
  if ((tid & 63) == 0) red[tid >> 6] = partial;
  __syncthreads();
  if (tid == 0)
    ws[b * NCH + chunk] = red[0] + red[1] + red[2] + red[3];
}

__global__ void vignet_reduce(const float* __restrict__ ws,
                              const float* __restrict__ dnsb,
                              float* __restrict__ out, int B)
{
  const int b = blockIdx.x * blockDim.x + threadIdx.x;
  if (b < B) {
    float s = dnsb[0];
#pragma unroll
    for (int c = 0; c < NCH; ++c) s += ws[b * NCH + c];
    out[b] = s;
  }
}

extern "C" void kernel_launch(void* const* d_in, const int* in_sizes, int n_in,
                              void* d_out, int out_size, void* d_ws, size_t ws_size,
                              hipStream_t stream) {
  const float* p[35];
  for (int i = 0; i < 35; ++i) p[i] = (const float*)d_in[i];
  const int B = in_sizes[0] / 2000;
  float* ws = (float*)d_ws;

  vignet_kernel<<<dim3(B * NCH), dim3(TPB), 0, stream>>>(
      p[0],
      p[1], p[2], p[3], p[4], p[5], p[6], p[7], p[8],
      p[9], p[10], p[11], p[12],
      p[13], p[14], p[15], p[16],
      p[17], p[18], p[19], p[20],
      p[21],                      // dns_w
      p[23], p[24], p[25], p[26],
      p[27], p[28], p[29], p[30],
      p[31], p[32], p[33], p[34],
      ws);

  vignet_reduce<<<dim3((B + TPB - 1) / TPB), dim3(TPB), 0, stream>>>(
      ws, p[22], (float*)d_out, B);
}

// Round 6
// 463.519 us; speedup vs baseline: 5.0048x; 5.0048x over previous
//
#include <hip/hip_runtime.h>

#define REP10(X) X(0) X(1) X(2) X(3) X(4) X(5) X(6) X(7) X(8) X(9)

// ---------------------------------------------------------------------------
// stage_kernel: one fused VIGNet stage, global->global, zero LDS, zero
// barriers, zero per-thread arrays (named scalars only).
// thread = (bc = blockIdx.z, o = blockIdx.y, t = blockIdx.x*256+tid)
// in : [bc][CIN][2][1000] ; out : [bc][10][2][1000] (t < Tout valid)
// All weight indices are wave-uniform -> scalar loads on the SMEM pipe.
// ---------------------------------------------------------------------------
template <int CIN>
__global__ __launch_bounds__(256) void stage_kernel(
    const float* __restrict__ in, float* __restrict__ outp, int Tout,
    const float* __restrict__ ck, const float* __restrict__ cb,
    const float* __restrict__ g,  const float* __restrict__ be,
    const float* __restrict__ mn, const float* __restrict__ vr,
    const float* __restrict__ aK, const float* __restrict__ ab,
    const float* __restrict__ adw, const float* __restrict__ adb)
{
  const int tt = blockIdx.x * 256 + threadIdx.x;
  if (tt >= Tout) return;
  const int o = blockIdx.y;
  const float* __restrict__ inb = in + (size_t)blockIdx.z * (CIN * 2000) + tt;

  // attention logits y_i = adb_i + sum_w adw[w,i] * m_i(t+w)
#define DECLY(i) float y##i = adb[i];
  REP10(DECLY)
#undef DECLY
#pragma unroll
  for (int w = 0; w < 5; ++w) {
#define DECLM(i) float m##i = ab[i * 2 + o];
    REP10(DECLM)
#undef DECLM
#pragma unroll
    for (int h = 0; h < 2; ++h)
#pragma unroll
      for (int ci = 0; ci < CIN; ++ci) {
        const float xin = inb[(ci * 2 + h) * 1000 + w];
#define FMAM(i) m##i += xin * aK[((i * 2 + h) * CIN + ci) * 2 + o];
        REP10(FMAM)
#undef FMAM
      }
#define FMAY(i) y##i += m##i * adw[w * 10 + i];
    REP10(FMAY)
#undef FMAY
  }

  // conv (1,5) valid, CIN -> 10
#define DECLC(i) float c##i = cb[i];
  REP10(DECLC)
#undef DECLC
#pragma unroll
  for (int w = 0; w < 5; ++w)
#pragma unroll
    for (int ci = 0; ci < CIN; ++ci) {
      const float xin = inb[(ci * 2 + o) * 1000 + w];
#define FMAC(i) c##i += xin * ck[(w * CIN + ci) * 10 + i];
      REP10(FMAC)
#undef FMAC
    }

  // softmax over the 10 heads, fully in-thread
  float mx = y0;
  mx = fmaxf(mx, y1); mx = fmaxf(mx, y2); mx = fmaxf(mx, y3);
  mx = fmaxf(mx, y4); mx = fmaxf(mx, y5); mx = fmaxf(mx, y6);
  mx = fmaxf(mx, y7); mx = fmaxf(mx, y8); mx = fmaxf(mx, y9);
#define DECLE(i) const float e##i = __expf(y##i - mx);
  REP10(DECLE)
#undef DECLE
  const float sm  = e0 + e1 + e2 + e3 + e4 + e5 + e6 + e7 + e8 + e9;
  const float inv = 1.0f / sm;

  // bn + leaky-relu + attention multiply + store
  float* __restrict__ ob = outp + (size_t)blockIdx.z * 20000 + o * 1000 + tt;
#define STORE(i) { const float sc = g[i] * rsqrtf(vr[i] + 1e-3f);              \
    float bv = c##i * sc + (be[i] - mn[i] * sc);                               \
    bv = (bv >= 0.f) ? bv : 0.2f * bv;                                         \
    ob[i * 2000] = bv * e##i * inv; }
  REP10(STORE)
#undef STORE
}

// ---------------------------------------------------------------------------
// final_kernel: conv4 (2,1) -> lrelu -> dot(dns_w) -> block reduce -> out[b]
// one block per batch element of the chunk
// ---------------------------------------------------------------------------
__global__ __launch_bounds__(256) void final_kernel(
    const float* __restrict__ h3,   // [bc][c][o][1000], t < 988 valid
    const float* __restrict__ c4k, const float* __restrict__ c4b,
    const float* __restrict__ dnsw, const float* __restrict__ dnsb,
    float* __restrict__ outp, int b0)
{
  __shared__ float red[4];
  const int tid = threadIdx.x;
  const float* __restrict__ hb = h3 + (size_t)blockIdx.x * 20000;
  float partial = 0.f;
  for (int t = tid; t < 988; t += 256) {
#define LOADX(i) const float xa##i = hb[i * 2000 + t];                         \
                 const float xb##i = hb[i * 2000 + 1000 + t];
    REP10(LOADX)
#undef LOADX
    const float* __restrict__ dwp = dnsw + t * 20;
    float dot = 0.f;
    for (int cc = 0; cc < 20; ++cc) {   // cc wave-uniform -> scalar weight loads
      float acc = c4b[cc];
#define FMA4(i) acc += xa##i * c4k[i * 20 + cc] + xb##i * c4k[(10 + i) * 20 + cc];
      REP10(FMA4)
#undef FMA4
      acc = (acc >= 0.f) ? acc : 0.2f * acc;
      dot += acc * dwp[cc];
    }
    partial += dot;
  }
#pragma unroll
  for (int off = 32; off > 0; off >>= 1)
    partial += __shfl_down(partial, off, 64);
  if ((tid & 63) == 0) red[tid >> 6] = partial;
  __syncthreads();
  if (tid == 0)
    outp[b0 + blockIdx.x] = red[0] + red[1] + red[2] + red[3] + dnsb[0];
}

extern "C" void kernel_launch(void* const* d_in, const int* in_sizes, int n_in,
                              void* d_out, int out_size, void* d_ws, size_t ws_size,
                              hipStream_t stream) {
  const float* p[35];
  for (int i = 0; i < 35; ++i) p[i] = (const float*)d_in[i];
  const int B = in_sizes[0] / 2000;

  // two ping-pong chunk buffers [CH][10][2][1000] f32; CH adapted to ws_size
  int CH = 1024;
  if (CH > B) CH = B;
  while ((size_t)CH * 160000ull > ws_size && CH > 1) CH >>= 1;
  float* hA = (float*)d_ws;
  float* hB = hA + (size_t)CH * 20000;

  for (int b0 = 0; b0 < B; b0 += CH) {
    const int cc = (B - b0 < CH) ? (B - b0) : CH;
    const dim3 blk(256);
    // stage1: x -> hA (Tout=996)
    stage_kernel<1><<<dim3(4, 2, cc), blk, 0, stream>>>(
        p[0] + (size_t)b0 * 2000, hA, 996,
        p[1], p[2], p[9], p[10], p[11], p[12], p[23], p[24], p[25], p[26]);
    // stage2: hA -> hB (Tout=992)
    stage_kernel<10><<<dim3(4, 2, cc), blk, 0, stream>>>(
        hA, hB, 992,
        p[3], p[4], p[13], p[14], p[15], p[16], p[27], p[28], p[29], p[30]);
    // stage3: hB -> hA (Tout=988)
    stage_kernel<10><<<dim3(4, 2, cc), blk, 0, stream>>>(
        hB, hA, 988,
        p[5], p[6], p[17], p[18], p[19], p[20], p[31], p[32], p[33], p[34]);
    // conv4 + dense head
    final_kernel<<<dim3(cc), blk, 0, stream>>>(
        hA, p[7], p[8], p[21], p[22], (float*)d_out, b0);
  }
}

// Round 7
// 222.478 us; speedup vs baseline: 10.4273x; 2.0834x over previous
//
#include <hip/hip_runtime.h>

#define REP10(X) X(0) X(1) X(2) X(3) X(4) X(5) X(6) X(7) X(8) X(9)

// ---------------------------------------------------------------------------
// stage_kernel: one fused VIGNet stage, LDS-staged per block, one barrier.
// grid = (ceil(Tout/256), 2, batch-chunk); block = 256 = one t-tile.
// in : [bc][CIN][2][1000] ; out : [bc][10][2][1000] (t < Tout valid)
// Phase A stages input rows and the MHRSSA einsum m (computed ONCE per
// position, vs 5x recompute in round 6 = the dominant redundant VALU work).
// Phase B: depthwise+softmax from smm, conv+BN+lrelu+mul from xb.
// Named scalars only (R1-R5: per-thread aggregates => phantom scratch traffic).
// ---------------------------------------------------------------------------
template <int CIN>
__global__ __launch_bounds__(256) void stage_kernel(
    const float* __restrict__ in, float* __restrict__ outp, int Tout,
    const float* __restrict__ ck, const float* __restrict__ cb,
    const float* __restrict__ g,  const float* __restrict__ be,
    const float* __restrict__ mn, const float* __restrict__ vr,
    const float* __restrict__ aK, const float* __restrict__ ab,
    const float* __restrict__ adw, const float* __restrict__ adb)
{
  __shared__ float xb[2 * CIN][264];   // staged input rows
  __shared__ float smm[10][264];       // staged einsum m_i(t)

  const int tid = threadIdx.x;
  const int o   = blockIdx.y;
  const int t0  = blockIdx.x * 256;
  const int Tin = Tout + 4;
  const float* __restrict__ inb = in + (size_t)blockIdx.z * (CIN * 2000);

  // ---- Phase A: positions [t0, t0+260) -> xb, smm
  for (int lt = tid; lt < 260; lt += 256) {
    const int t = t0 + lt;
    if (t < Tin) {
#define DECLM(i) float m##i = ab[i * 2 + o];
      REP10(DECLM)
#undef DECLM
#pragma unroll
      for (int h = 0; h < 2; ++h)
#pragma unroll
        for (int ci = 0; ci < CIN; ++ci) {
          const float xin = inb[(ci * 2 + h) * 1000 + t];
          xb[ci * 2 + h][lt] = xin;
#define FMAM(i) m##i += xin * aK[((i * 2 + h) * CIN + ci) * 2 + o];
          REP10(FMAM)
#undef FMAM
        }
#define STM(i) smm[i][lt] = m##i;
      REP10(STM)
#undef STM
    }
  }
  __syncthreads();

  // ---- Phase B (no more barriers -> early-out safe)
  const int tt = t0 + tid;
  if (tt >= Tout) return;
  const int lt = tid;

  // depthwise (1,5) from smm
#define DECLY(i) float y##i = adb[i];
  REP10(DECLY)
#undef DECLY
#pragma unroll
  for (int w = 0; w < 5; ++w) {
#define FMAY(i) y##i += smm[i][lt + w] * adw[w * 10 + i];
    REP10(FMAY)
#undef FMAY
  }

  // conv (1,5) valid, CIN -> 10, from xb
#define DECLC(i) float c##i = cb[i];
  REP10(DECLC)
#undef DECLC
#pragma unroll
  for (int w = 0; w < 5; ++w)
#pragma unroll
    for (int ci = 0; ci < CIN; ++ci) {
      const float xin = xb[ci * 2 + o][lt + w];
#define FMAC(i) c##i += xin * ck[(w * CIN + ci) * 10 + i];
      REP10(FMAC)
#undef FMAC
    }

  // softmax over the 10 heads, fully in-thread
  float mx = y0;
  mx = fmaxf(mx, y1); mx = fmaxf(mx, y2); mx = fmaxf(mx, y3);
  mx = fmaxf(mx, y4); mx = fmaxf(mx, y5); mx = fmaxf(mx, y6);
  mx = fmaxf(mx, y7); mx = fmaxf(mx, y8); mx = fmaxf(mx, y9);
#define DECLE(i) const float e##i = __expf(y##i - mx);
  REP10(DECLE)
#undef DECLE
  const float sm  = e0 + e1 + e2 + e3 + e4 + e5 + e6 + e7 + e8 + e9;
  const float inv = 1.0f / sm;

  // bn + leaky-relu + attention multiply + store
  float* __restrict__ ob = outp + (size_t)blockIdx.z * 20000 + o * 1000 + tt;
#define STORE(i) { const float sc = g[i] * rsqrtf(vr[i] + 1e-3f);              \
    float bv = c##i * sc + (be[i] - mn[i] * sc);                               \
    bv = (bv >= 0.f) ? bv : 0.2f * bv;                                         \
    ob[i * 2000] = bv * e##i * inv; }
  REP10(STORE)
#undef STORE
}

// ---------------------------------------------------------------------------
// final_kernel: conv4 (2,1) -> lrelu -> dot(dns_w) -> block reduce -> out[b]
// ---------------------------------------------------------------------------
__global__ __launch_bounds__(256) void final_kernel(
    const float* __restrict__ h3,   // [bc][c][o][1000], t < 988 valid
    const float* __restrict__ c4k, const float* __restrict__ c4b,
    const float* __restrict__ dnsw, const float* __restrict__ dnsb,
    float* __restrict__ outp, int b0)
{
  __shared__ float red[4];
  const int tid = threadIdx.x;
  const float* __restrict__ hb = h3 + (size_t)blockIdx.x * 20000;
  float partial = 0.f;
  for (int t = tid; t < 988; t += 256) {
#define LOADX(i) const float xa##i = hb[i * 2000 + t];                         \
                 const float xb##i = hb[i * 2000 + 1000 + t];
    REP10(LOADX)
#undef LOADX
    const float* __restrict__ dwp = dnsw + t * 20;
    float dot = 0.f;
    for (int cc = 0; cc < 20; ++cc) {   // cc wave-uniform -> scalar weight loads
      float acc = c4b[cc];
#define FMA4(i) acc += xa##i * c4k[i * 20 + cc] + xb##i * c4k[(10 + i) * 20 + cc];
      REP10(FMA4)
#undef FMA4
      acc = (acc >= 0.f) ? acc : 0.2f * acc;
      dot += acc * dwp[cc];
    }
    partial += dot;
  }
#pragma unroll
  for (int off = 32; off > 0; off >>= 1)
    partial += __shfl_down(partial, off, 64);
  if ((tid & 63) == 0) red[tid >> 6] = partial;
  __syncthreads();
  if (tid == 0)
    outp[b0 + blockIdx.x] = red[0] + red[1] + red[2] + red[3] + dnsb[0];
}

extern "C" void kernel_launch(void* const* d_in, const int* in_sizes, int n_in,
                              void* d_out, int out_size, void* d_ws, size_t ws_size,
                              hipStream_t stream) {
  const float* p[35];
  for (int i = 0; i < 35; ++i) p[i] = (const float*)d_in[i];
  const int B = in_sizes[0] / 2000;

  // two ping-pong chunk buffers [CH][10][2][1000] f32; CH adapted to ws_size
  int CH = 1024;
  if (CH > B) CH = B;
  while ((size_t)CH * 160000ull > ws_size && CH > 1) CH >>= 1;
  float* hA = (float*)d_ws;
  float* hB = hA + (size_t)CH * 20000;

  for (int b0 = 0; b0 < B; b0 += CH) {
    const int cc = (B - b0 < CH) ? (B - b0) : CH;
    const dim3 blk(256);
    // stage1: x -> hA (Tout=996)
    stage_kernel<1><<<dim3(4, 2, cc), blk, 0, stream>>>(
        p[0] + (size_t)b0 * 2000, hA, 996,
        p[1], p[2], p[9], p[10], p[11], p[12], p[23], p[24], p[25], p[26]);
    // stage2: hA -> hB (Tout=992)
    stage_kernel<10><<<dim3(4, 2, cc), blk, 0, stream>>>(
        hA, hB, 992,
        p[3], p[4], p[13], p[14], p[15], p[16], p[27], p[28], p[29], p[30]);
    // stage3: hB -> hA (Tout=988)
    stage_kernel<10><<<dim3(4, 2, cc), blk, 0, stream>>>(
        hB, hA, 988,
        p[5], p[6], p[17], p[18], p[19], p[20], p[31], p[32], p[33], p[34]);
    // conv4 + dense head
    final_kernel<<<dim3(cc), blk, 0, stream>>>(
        hA, p[7], p[8], p[21], p[22], (float*)d_out, b0);
  }
}

// Round 8
// 216.005 us; speedup vs baseline: 10.7397x; 1.0300x over previous
//
#include <hip/hip_runtime.h>

#define REP10(X) X(0) X(1) X(2) X(3) X(4) X(5) X(6) X(7) X(8) X(9)

// ---------------------------------------------------------------------------
// prep_kernel: fold BN+conv-bias into scale/shift2, pre-scale attn dw/db by
// log2(e) so the softmax uses native exp2. One tiny launch, runs every call.
// consts layout per stage (stride 80): [0..10) scale | [10..20) shift2 |
// [20..70) adw2[w*10+i] | [70..80) adb2[i]
// ---------------------------------------------------------------------------
__device__ __forceinline__ void fold_stage(
    float* dst, const float* g, const float* be, const float* mn,
    const float* vr, const float* cb, const float* adw, const float* adb)
{
  const int tid = threadIdx.x;
  if (tid < 10) {
    const float sc = g[tid] * rsqrtf(vr[tid] + 1e-3f);
    dst[tid]      = sc;
    dst[10 + tid] = (cb[tid] - mn[tid]) * sc + be[tid];
    dst[70 + tid] = adb[tid] * 1.44269504088896340736f;
  }
  if (tid >= 10 && tid < 60)
    dst[10 + tid] = adw[tid - 10] * 1.44269504088896340736f;
}

__global__ void prep_kernel(
    const float* g1, const float* be1, const float* m1, const float* v1,
    const float* cb1, const float* a1dw, const float* a1db,
    const float* g2, const float* be2, const float* m2, const float* v2,
    const float* cb2, const float* a2dw, const float* a2db,
    const float* g3, const float* be3, const float* m3, const float* v3,
    const float* cb3, const float* a3dw, const float* a3db,
    float* consts)
{
  fold_stage(consts,       g1, be1, m1, v1, cb1, a1dw, a1db);
  fold_stage(consts + 80,  g2, be2, m2, v2, cb2, a2dw, a2db);
  fold_stage(consts + 160, g3, be3, m3, v3, cb3, a3dw, a3db);
}

// ---------------------------------------------------------------------------
// stage_kernel: one fused VIGNet stage. LDS holds ONLY the staged einsum m
// (10.5 KB -> wave-cap occupancy); conv re-reads x from global (L1-resident:
// ~10.6 KB per block working set, primed by Phase A).
// grid = (ceil(Tout/256), 2, batch-chunk); thread = one t position.
// in : [bc][CIN][2][1000] ; out : [bc][10][2][1000]
// ---------------------------------------------------------------------------
template <int CIN>
__global__ __launch_bounds__(256) void stage_kernel(
    const float* __restrict__ in, float* __restrict__ outp, int Tout,
    const float* __restrict__ ck,   // conv kernel (raw)
    const float* __restrict__ aK, const float* __restrict__ ab,  // einsum raw
    const float* __restrict__ cst)  // folded consts for this stage
{
  __shared__ float smm[10][264];

  const int tid = threadIdx.x;
  const int o   = blockIdx.y;
  const int t0  = blockIdx.x * 256;
  const int Tin = Tout + 4;
  const float* __restrict__ inb = in + (size_t)blockIdx.z * (CIN * 2000);

  // ---- Phase A: einsum m_i(t) for positions [t0, t0+260) -> smm
  for (int lt = tid; lt < 260; lt += 256) {
    const int t = t0 + lt;
    if (t < Tin) {
#define DECLM(i) float m##i = ab[i * 2 + o];
      REP10(DECLM)
#undef DECLM
#pragma unroll
      for (int h = 0; h < 2; ++h)
#pragma unroll
        for (int ci = 0; ci < CIN; ++ci) {
          const float xin = inb[(ci * 2 + h) * 1000 + t];
#define FMAM(i) m##i += xin * aK[((i * 2 + h) * CIN + ci) * 2 + o];
          REP10(FMAM)
#undef FMAM
        }
#define STM(i) smm[i][lt] = m##i;
      REP10(STM)
#undef STM
    }
  }
  __syncthreads();

  // ---- Phase B (no more barriers -> early-out safe)
  const int tt = t0 + tid;
  if (tt >= Tout) return;

  const float* __restrict__ scale  = cst;
  const float* __restrict__ shift2 = cst + 10;
  const float* __restrict__ adw2   = cst + 20;
  const float* __restrict__ adb2   = cst + 70;

  // depthwise (1,5) from smm (already in log2e-scaled space)
#define DECLY(i) float y##i = adb2[i];
  REP10(DECLY)
#undef DECLY
#pragma unroll
  for (int w = 0; w < 5; ++w) {
#define FMAY(i) y##i += smm[i][tid + w] * adw2[w * 10 + i];
    REP10(FMAY)
#undef FMAY
  }

  // conv (1,5) valid, CIN -> 10, reading x from global (L1-hot)
#define DECLC(i) float c##i = 0.f;
  REP10(DECLC)
#undef DECLC
  const float* __restrict__ cinb = inb + o * 1000 + tt;
#pragma unroll
  for (int w = 0; w < 5; ++w)
#pragma unroll
    for (int ci = 0; ci < CIN; ++ci) {
      const float xin = cinb[ci * 2000 + w];
#define FMAC(i) c##i += xin * ck[(w * CIN + ci) * 10 + i];
      REP10(FMAC)
#undef FMAC
    }

  // softmax over the 10 heads via native exp2 (weights pre-scaled by log2e)
  float mx = y0;
  mx = fmaxf(mx, y1); mx = fmaxf(mx, y2); mx = fmaxf(mx, y3);
  mx = fmaxf(mx, y4); mx = fmaxf(mx, y5); mx = fmaxf(mx, y6);
  mx = fmaxf(mx, y7); mx = fmaxf(mx, y8); mx = fmaxf(mx, y9);
#define DECLE(i) const float e##i = exp2f(y##i - mx);
  REP10(DECLE)
#undef DECLE
  const float sm  = e0 + e1 + e2 + e3 + e4 + e5 + e6 + e7 + e8 + e9;
  const float inv = 1.0f / sm;

  // folded bn (+conv bias) + leaky-relu (max identity) + attn mul + store
  float* __restrict__ ob = outp + (size_t)blockIdx.z * 20000 + o * 1000 + tt;
#define STORE(i) { float bv = c##i * scale[i] + shift2[i];                     \
    bv = fmaxf(bv, 0.2f * bv);                                                 \
    ob[i * 2000] = bv * e##i * inv; }
  REP10(STORE)
#undef STORE
}

// ---------------------------------------------------------------------------
// final_kernel: conv4 (2,1) -> lrelu -> dot(dns_w) -> block reduce -> out[b]
// ---------------------------------------------------------------------------
__global__ __launch_bounds__(256) void final_kernel(
    const float* __restrict__ h3,   // [bc][c][o][1000], t < 988 valid
    const float* __restrict__ c4k, const float* __restrict__ c4b,
    const float* __restrict__ dnsw, const float* __restrict__ dnsb,
    float* __restrict__ outp, int b0)
{
  __shared__ float red[4];
  const int tid = threadIdx.x;
  const float* __restrict__ hb = h3 + (size_t)blockIdx.x * 20000;
  float partial = 0.f;
  for (int t = tid; t < 988; t += 256) {
#define LOADX(i) const float xa##i = hb[i * 2000 + t];                         \
                 const float xb##i = hb[i * 2000 + 1000 + t];
    REP10(LOADX)
#undef LOADX
    const float* __restrict__ dwp = dnsw + t * 20;
    float dot = 0.f;
    for (int cc = 0; cc < 20; ++cc) {   // cc wave-uniform -> scalar weight loads
      float acc = c4b[cc];
#define FMA4(i) acc += xa##i * c4k[i * 20 + cc] + xb##i * c4k[(10 + i) * 20 + cc];
      REP10(FMA4)
#undef FMA4
      acc = fmaxf(acc, 0.2f * acc);
      dot += acc * dwp[cc];
    }
    partial += dot;
  }
#pragma unroll
  for (int off = 32; off > 0; off >>= 1)
    partial += __shfl_down(partial, off, 64);
  if ((tid & 63) == 0) red[tid >> 6] = partial;
  __syncthreads();
  if (tid == 0)
    outp[b0 + blockIdx.x] = red[0] + red[1] + red[2] + red[3] + dnsb[0];
}

extern "C" void kernel_launch(void* const* d_in, const int* in_sizes, int n_in,
                              void* d_out, int out_size, void* d_ws, size_t ws_size,
                              hipStream_t stream) {
  const float* p[35];
  for (int i = 0; i < 35; ++i) p[i] = (const float*)d_in[i];
  const int B = in_sizes[0] / 2000;

  // ws: [0..256) floats = folded consts; then two ping-pong chunk buffers
  float* consts = (float*)d_ws;
  const size_t ws_rem = ws_size - 1024;
  int CH = 1024;
  if (CH > B) CH = B;
  while ((size_t)CH * 160000ull > ws_rem && CH > 1) CH >>= 1;
  float* hA = consts + 256;
  float* hB = hA + (size_t)CH * 20000;

  prep_kernel<<<dim3(1), dim3(64), 0, stream>>>(
      p[9], p[10], p[11], p[12], p[2], p[25], p[26],
      p[13], p[14], p[15], p[16], p[4], p[29], p[30],
      p[17], p[18], p[19], p[20], p[6], p[33], p[34],
      consts);

  for (int b0 = 0; b0 < B; b0 += CH) {
    const int cc = (B - b0 < CH) ? (B - b0) : CH;
    const dim3 blk(256);
    // stage1: x -> hA (Tout=996)
    stage_kernel<1><<<dim3(4, 2, cc), blk, 0, stream>>>(
        p[0] + (size_t)b0 * 2000, hA, 996, p[1], p[23], p[24], consts);
    // stage2: hA -> hB (Tout=992)
    stage_kernel<10><<<dim3(4, 2, cc), blk, 0, stream>>>(
        hA, hB, 992, p[3], p[27], p[28], consts + 80);
    // stage3: hB -> hA (Tout=988)
    stage_kernel<10><<<dim3(4, 2, cc), blk, 0, stream>>>(
        hB, hA, 988, p[5], p[31], p[32], consts + 160);
    // conv4 + dense head
    final_kernel<<<dim3(cc), blk, 0, stream>>>(
        hA, p[7], p[8], p[21], p[22], (float*)d_out, b0);
  }
}